// Round 12
// baseline (227.425 us; speedup 1.0000x reference)
//
#include <hip/hip_runtime.h>

#define T_LEN 256
#define D_IN 4

typedef __fp16 h8 __attribute__((ext_vector_type(8)));
typedef __fp16 cvt2_t __attribute__((ext_vector_type(2)));
typedef float float4v __attribute__((ext_vector_type(4)));

struct CellW { const float *Wih, *Whh, *bih, *bhh; };
struct Params {
    CellW c[6];
    const float* y;
    const float* Wout;
    const float* bout;
    float* out;
};

__device__ __forceinline__ float fexp2(float x) { return __builtin_amdgcn_exp2f(x); }
__device__ __forceinline__ float frcp(float x)  { return __builtin_amdgcn_rcpf(x); }
__device__ __forceinline__ int packh(float a, float b) {
    cvt2_t p = __builtin_amdgcn_cvt_pkrtz(a, b);
    return __builtin_bit_cast(int, p);
}
__device__ __forceinline__ h8 mk8(int a, int b, int c, int d) {
    int4 v; v.x = a; v.y = b; v.z = c; v.w = d;
    return __builtin_bit_cast(h8, v);
}

// R12 barrier: lgkm-only drain + raw s_barrier. __syncthreads would emit
// s_waitcnt vmcnt(0) before s_barrier (guide §5 m97), draining the in-flight
// x prefetch EVERY step (~150-200cy L2 latency on the block's pace path).
// Only LDS (h_sl) crosses waves -> lgkmcnt(0) suffices; global x loads stay
// in flight across barriers (AITER/HK pattern). sched_barrier(0) fences stop
// the scheduler from hoisting next-step LDS reads above the barrier (rule #18).
__device__ __forceinline__ void bar_nodrain() {
    __builtin_amdgcn_sched_barrier(0);
    asm volatile("s_waitcnt lgkmcnt(0)" ::: "memory");
    __builtin_amdgcn_s_barrier();
    __builtin_amdgcn_sched_barrier(0);
}

// K=32 MFMA, unit-gate-packed A with pi input-column permutation + e-swap
// (R7-R11 proven): A row m -> (local unit m>>2, gate m&3); D lane(n,Q) reg r
// = gate r of local unit Q, batch col n. MFMA j covers global units 8e+4j+Q.
// B operand uniformly mk8(ownpk, sib, pv0, pv1) for both e-halves.
#define MFMA32(a, b, c) __builtin_amdgcn_mfma_f32_16x16x32_f16(a, b, c, 0, 0, 0)

// Activation for 2 units (R6-R11-proven, bitwise unchanged). p[0..3]=i,f,g,o
// pre-scaled by -log2e (i,f,o) / -2log2e (g), folded into A/bias. c-path
// common-denominator fusion, rcp paired across the 2 units: 10 exp2 + 2 rcp.
// Range audit (|pre| <= ~8): den<=2^47, pair<=2^94 < 2^128; Dh<=2^42
// (ec clamp 2^30), pair<2^84. No cancellation: err(c') ~ eps*max|fc|,|ig|.
__device__ __forceinline__ void act2(const float4v& pA, const float4v& pB,
                                     float& cA, float& cB,
                                     float& hA, float& hB) {
    float eiA = fexp2(pA[0]), efA = fexp2(pA[1]), egA = fexp2(pA[2]);
    float eiB = fexp2(pB[0]), efB = fexp2(pB[1]), egB = fexp2(pB[2]);
    float FA = 1.f + efA,              FB = 1.f + efB;
    float PA = (1.f + eiA) * (1.f + egA), PB = (1.f + eiB) * (1.f + egB);
    float NGA = 1.f - egA,             NGB = 1.f - egB;
    float denA = FA * PA,              denB = FB * PB;
    float numA = fmaf(cA, PA, NGA * FA);
    float numB = fmaf(cB, PB, NGB * FB);
    float RC = frcp(denA * denB);
    cA = numA * denB * RC;
    cB = numB * denA * RC;
    const float K2 = -2.8853900817779268f;     // -2*log2e
    float eoA = fexp2(pA[3]), ecA = fexp2(fminf(cA * K2, 30.f));
    float eoB = fexp2(pB[3]), ecB = fexp2(fminf(cB * K2, 30.f));
    float NOA = 1.f - ecA,    NOB = 1.f - ecB;
    float DhA = (1.f + eoA) * (1.f + ecA);
    float DhB = (1.f + eoB) * (1.f + ecB);
    float RH = frcp(DhA * DhB);
    hA = NOA * DhB * RH;
    hB = NOB * DhA * RH;
}

// R12 = R11's 12-wave block (2dir x 3layer x 2e; 3 waves/SIMD uniform -- the
// unique optimal partition) with the barrier drain fixed:
//  - per-step sync = bar_nodrain() (lgkm-only): x loads live across barriers
//  - x kept as RAW float4 in registers; packed at consumption (2 steps after
//    issue) -> compiler emits precise vmcnt(1) there, fully covered
//  - everything else (A-frags, act2, slab layout, parity protocol, fused
//    out_proj) bit-for-bit R11.
__global__ void __launch_bounds__(768)
__attribute__((amdgpu_waves_per_eu(3, 4)))
lstm_wf_kernel(Params p)
{
    __shared__ int h_sl[2][2][3][2][4][16];    // [par][dir][l][e][Q][n] 6KB
    __shared__ float hf[16][33];               // f32 h3 staging, +1 pad

    const int tid = threadIdx.x;
    const int v = tid >> 6;         // wave 0..11
    const int dir = (v >= 6);
    const int v6 = v - 6 * dir;
    const int l = v6 >> 1;          // layer 0..2
    const int e = v6 & 1;           // unit-half: units 8e..8e+7
    const int L = tid & 63;
    const int n = L & 15;           // batch col
    const int Q = L >> 4;

    const int b0 = blockIdx.x * 16;
    const CellW cw = p.c[dir * 3 + l];
    const float LOG2E = 1.4426950408889634f;

    // ---- prepass: zero h slab (both parities) ----
    for (int i = tid; i < 2 * 2 * 3 * 2 * 4 * 16; i += 768)
        ((int*)h_sl)[i] = 0;

    // ---- A-frags: row n -> (local unit n>>2, gate n&3). Own-side columns
    // pi + e-swap; prev-side columns natural pi. (R11-proven) ----
    const int gate = n & 3;
    const int su = n >> 2;
    const float sA = (gate == 2) ? -2.f * LOG2E : -LOG2E;
    h8 A8[2];
    float4v bs[2];
#pragma unroll
    for (int j = 0; j < 2; ++j) {
        const int u = 8 * e + 4 * j + su;   // A-row unit
        const int row = gate * 16 + u;
        float vh[4], vp[4];
#pragma unroll
        for (int i = 0; i < 4; ++i) {
            const int colh = 4 * ((i + 2 * e) & 3) + Q;  // own-side, e-swapped
            vh[i] = cw.Whh[row * 16 + colh];
            vp[i] = (l == 0) ? ((Q == 0) ? cw.Wih[row * D_IN + i] : 0.f)
                             : cw.Wih[row * 16 + 4 * i + Q];  // prev, natural
        }
        A8[j] = mk8(packh(vh[0] * sA, vh[1] * sA), packh(vh[2] * sA, vh[3] * sA),
                    packh(vp[0] * sA, vp[1] * sA), packh(vp[2] * sA, vp[3] * sA));
        const int ub = 8 * e + 4 * j + Q;   // D reg r = gate r of unit ub
        const float br0 = cw.bih[0 * 16 + ub] + cw.bhh[0 * 16 + ub];
        const float br1 = cw.bih[1 * 16 + ub] + cw.bhh[1 * 16 + ub];
        const float br2 = cw.bih[2 * 16 + ub] + cw.bhh[2 * 16 + ub];
        const float br3 = cw.bih[3 * 16 + ub] + cw.bhh[3 * 16 + ub];
        bs[j] = (float4v){br0 * -LOG2E, br1 * -LOG2E,
                          br2 * -2.f * LOG2E, br3 * -LOG2E};
    }

    // ---- x prologue: raw float4 for t=0 -> xf0, t=1 -> xf1 (l0, L<16).
    // Other lanes keep zeros -> packh(0,0)=0 reproduces the zero operand. ----
    const float* ybase = p.y + (size_t)(b0 + n) * (T_LEN * D_IN);
    float4 xf0 = {0.f, 0.f, 0.f, 0.f}, xf1 = {0.f, 0.f, 0.f, 0.f};
    if (l == 0 && L < 16) {
        const int ta = dir ? (T_LEN - 1) : 0;
        const int tb = dir ? (T_LEN - 2) : 1;
        xf0 = *(const float4*)(ybase + (size_t)ta * D_IN);
        xf1 = *(const float4*)(ybase + (size_t)tb * D_IN);
    }

    bar_nodrain();                   // prepass visible (LDS only)

    float cA = 0.f, cB = 0.f;        // cell state: units 8e+Q, 8e+4+Q
    float hA = 0.f, hB = 0.f;
    int ownpk = 0;                   // own e-half packed h (register)

    // One step. pr/pw literals at every call site -> static parity.
    auto STEP = [&](int s, int pr, int pw, bool a0, bool a1, bool a2,
                    float4& xf) {
        const bool act = (l == 0) ? a0 : (l == 1) ? a1 : a2;  // wave-uniform
        if (act) {
            const int sib = h_sl[pr][dir][l][1 - e][Q][n];
            int pv0, pv1;
            if (l == 0) {
                pv0 = packh(xf.x, xf.y);        // vmcnt wait lands here,
                pv1 = packh(xf.z, xf.w);        // 2 barriers after issue
            } else {
                pv0 = h_sl[pr][dir][l - 1][0][Q][n];   // 256B apart ->
                pv1 = h_sl[pr][dir][l - 1][1][Q][n];   // read2st64 candidate
            }
            // issue x load for step s+2 (stays in flight across barriers)
            if (l == 0 && L < 16) {
                const int t2 = s + 2;
                if (t2 < T_LEN) {
                    const int tt = dir ? (T_LEN - 1 - t2) : t2;
                    xf = *(const float4*)(ybase + (size_t)tt * D_IN);
                }
            }
            const h8 b8 = mk8(ownpk, sib, pv0, pv1);   // uniform for both e
            float4v p0 = MFMA32(A8[0], b8, bs[0]);     // gates of unit 8e+Q
            float4v p1 = MFMA32(A8[1], b8, bs[1]);     // gates of unit 8e+4+Q
            act2(p0, p1, cA, cB, hA, hB);
            ownpk = packh(hA, hB);
            h_sl[pw][dir][l][e][Q][n] = ownpk;
        }
        bar_nodrain();
    };

    // prologue (guarded): s=0 (l0), s=1 (l0,l1)
    STEP(0, 1, 0, true, false, false, xf0);
    STEP(1, 0, 1, true, true, false, xf1);

    // main loop: s=2..255, all layers active, branch-free, 2-step unroll
#pragma unroll 1
    for (int s = 2; s < T_LEN; s += 2) {
        STEP(s,     1, 0, true, true, true, xf0);
        STEP(s + 1, 0, 1, true, true, true, xf1);
    }

    // epilogue (guarded): s=256 (l1,l2), s=257 (l2)
    STEP(256, 1, 0, false, true, true, xf0);
    STEP(257, 0, 1, false, false, true, xf1);

    // ---- fused out_proj ----
    // l2 waves stage f32 h3 (units 8e+Q, 8e+4+Q of chain n, per dir)
    if (l == 2) {
        hf[n][dir * 16 + 8 * e + Q]     = hA;
        hf[n][dir * 16 + 8 * e + 4 + Q] = hB;
    }
    __syncthreads();                 // once; full drain is fine here
    if (tid < 64) {
        const int cn = tid >> 2, o = tid & 3;
        float acc = p.bout[o];
        const float* w = p.Wout + o * 32;
#pragma unroll
        for (int m = 0; m < 32; ++m) acc = fmaf(hf[cn][m], w[m], acc);
        p.out[(size_t)(b0 + cn) * 4 + o] = acc;
    }
}

extern "C" void kernel_launch(void* const* d_in, const int* in_sizes, int n_in,
                              void* d_out, int out_size, void* d_ws, size_t ws_size,
                              hipStream_t stream)
{
    const int B = in_sizes[0] / (T_LEN * D_IN); // 4096

    Params p;
    for (int s = 0; s < 6; ++s) {
        p.c[s].Wih = (const float*)d_in[1 + 4 * s];
        p.c[s].Whh = (const float*)d_in[2 + 4 * s];
        p.c[s].bih = (const float*)d_in[3 + 4 * s];
        p.c[s].bhh = (const float*)d_in[4 + 4 * s];
    }
    p.y = (const float*)d_in[0];
    p.Wout = (const float*)d_in[25];
    p.bout = (const float*)d_in[26];
    p.out = (float*)d_out;

    const int blocks = B / 16;               // 16 chains + both dirs per block
    lstm_wf_kernel<<<blocks, 768, 0, stream>>>(p);
}

// Round 13
// 220.006 us; speedup vs baseline: 1.0337x; 1.0337x over previous
//
#include <hip/hip_runtime.h>

#define T_LEN 256
#define D_IN 4

typedef __fp16 h8 __attribute__((ext_vector_type(8)));
typedef __fp16 cvt2_t __attribute__((ext_vector_type(2)));
typedef float float4v __attribute__((ext_vector_type(4)));

struct CellW { const float *Wih, *Whh, *bih, *bhh; };
struct Params {
    CellW c[6];
    const float* y;
    const float* Wout;
    const float* bout;
    float* out;
};

__device__ __forceinline__ float fexp2(float x) { return __builtin_amdgcn_exp2f(x); }
__device__ __forceinline__ float frcp(float x)  { return __builtin_amdgcn_rcpf(x); }
__device__ __forceinline__ int packh(float a, float b) {
    cvt2_t p = __builtin_amdgcn_cvt_pkrtz(a, b);
    return __builtin_bit_cast(int, p);
}
__device__ __forceinline__ h8 mk8(int a, int b, int c, int d) {
    int4 v; v.x = a; v.y = b; v.z = c; v.w = d;
    return __builtin_bit_cast(h8, v);
}

// K=32 MFMA, unit-gate-packed A with pi input-column permutation (R7-R10
// proven): A row m -> (local unit m>>2, gate m&3); D lane(n,Q) reg r = gate r
// of local unit Q, batch col n. MFMA j covers global units 8e+4j+Q.
// pi: k-slot 4Q+i <-> input unit 4i+Q. R11: the OWN-side (Whh) columns are
// additionally e-swapped (col = 4*((i+2e)&3)+Q) so that for BOTH e-halves
// the B operand is uniformly mk8(ownpk, sib, pv0, pv1) -- own pack always in
// dword0 -- removing the per-step e-cndmasks. Prev-side (Wih l>0) keeps
// natural pi (pv0 = e0-pack, pv1 = e1-pack, fixed). Exact reindex of the dot
// product -> bitwise identical results.
#define MFMA32(a, b, c) __builtin_amdgcn_mfma_f32_16x16x32_f16(a, b, c, 0, 0, 0)

// Activation for 2 units (R6-R11-proven, bitwise unchanged). p[0..3]=i,f,g,o
// pre-scaled by -log2e (i,f,o) / -2log2e (g), folded into A/bias. c-path
// common-denominator fusion, rcp paired across the 2 units: 10 exp2 + 2 rcp.
// Range audit (|pre| <= ~8): den<=2^47, pair<=2^94 < 2^128; Dh<=2^42
// (ec clamp 2^30), pair<2^84. No cancellation: err(c') ~ eps*max(|fc|,|ig|).
__device__ __forceinline__ void act2(const float4v& pA, const float4v& pB,
                                     float& cA, float& cB,
                                     float& hA, float& hB) {
    float eiA = fexp2(pA[0]), efA = fexp2(pA[1]), egA = fexp2(pA[2]);
    float eiB = fexp2(pB[0]), efB = fexp2(pB[1]), egB = fexp2(pB[2]);
    float FA = 1.f + efA,              FB = 1.f + efB;
    float PA = (1.f + eiA) * (1.f + egA), PB = (1.f + eiB) * (1.f + egB);
    float NGA = 1.f - egA,             NGB = 1.f - egB;
    float denA = FA * PA,              denB = FB * PB;
    float numA = fmaf(cA, PA, NGA * FA);
    float numB = fmaf(cB, PB, NGB * FB);
    float RC = frcp(denA * denB);
    cA = numA * denB * RC;
    cB = numB * denA * RC;
    const float K2 = -2.8853900817779268f;     // -2*log2e
    float eoA = fexp2(pA[3]), ecA = fexp2(fminf(cA * K2, 30.f));
    float eoB = fexp2(pB[3]), ecB = fexp2(fminf(cB * K2, 30.f));
    float NOA = 1.f - ecA,    NOB = 1.f - ecB;
    float DhA = (1.f + eoA) * (1.f + ecA);
    float DhB = (1.f + eoB) * (1.f + ecB);
    float RH = frcp(DhA * DhB);
    hA = NOA * DhB * RH;
    hB = NOB * DhA * RH;
}

// R13 = R11 verbatim (best proven: 123.5us kernel / 220.9us total).
// R12's lgkm-only barrier + sched_barrier fences regressed (+5us): the vmcnt
// drain was NOT on the pace path (4/12 waves, L2-covered by barrier arrival),
// while the 258x sched_barrier(0) pins defeated the compiler's scheduling.
// Structure: 12-wave block (2dir x 3layer x 2e), 3 waves/SIMD uniform barrier
// group -- the unique optimal partition of 3072 equal wave-tasks; per-step
// parity double-buffer + 1 __syncthreads; register own-pack; 2-step-ahead
// x prefetch; branch-free main loop; fused out_proj.
__global__ void __launch_bounds__(768)
__attribute__((amdgpu_waves_per_eu(3, 4)))
lstm_wf_kernel(Params p)
{
    __shared__ int h_sl[2][2][3][2][4][16];    // [par][dir][l][e][Q][n] 6KB
    __shared__ float hf[16][33];               // f32 h3 staging, +1 pad

    const int tid = threadIdx.x;
    const int v = tid >> 6;         // wave 0..11
    const int dir = (v >= 6);
    const int v6 = v - 6 * dir;
    const int l = v6 >> 1;          // layer 0..2
    const int e = v6 & 1;           // unit-half: units 8e..8e+7
    const int L = tid & 63;
    const int n = L & 15;           // batch col
    const int Q = L >> 4;

    const int b0 = blockIdx.x * 16;
    const CellW cw = p.c[dir * 3 + l];
    const float LOG2E = 1.4426950408889634f;

    // ---- prepass: zero h slab (both parities) ----
    for (int i = tid; i < 2 * 2 * 3 * 2 * 4 * 16; i += 768)
        ((int*)h_sl)[i] = 0;

    // ---- A-frags: row n -> (local unit n>>2, gate n&3). Own-side columns
    // pi + e-swap; prev-side columns natural pi. ----
    const int gate = n & 3;
    const int su = n >> 2;
    const float sA = (gate == 2) ? -2.f * LOG2E : -LOG2E;
    h8 A8[2];
    float4v bs[2];
#pragma unroll
    for (int j = 0; j < 2; ++j) {
        const int u = 8 * e + 4 * j + su;   // A-row unit
        const int row = gate * 16 + u;
        float vh[4], vp[4];
#pragma unroll
        for (int i = 0; i < 4; ++i) {
            const int colh = 4 * ((i + 2 * e) & 3) + Q;  // own-side, e-swapped
            vh[i] = cw.Whh[row * 16 + colh];
            vp[i] = (l == 0) ? ((Q == 0) ? cw.Wih[row * D_IN + i] : 0.f)
                             : cw.Wih[row * 16 + 4 * i + Q];  // prev, natural
        }
        A8[j] = mk8(packh(vh[0] * sA, vh[1] * sA), packh(vh[2] * sA, vh[3] * sA),
                    packh(vp[0] * sA, vp[1] * sA), packh(vp[2] * sA, vp[3] * sA));
        const int ub = 8 * e + 4 * j + Q;   // D reg r = gate r of unit ub
        const float br0 = cw.bih[0 * 16 + ub] + cw.bhh[0 * 16 + ub];
        const float br1 = cw.bih[1 * 16 + ub] + cw.bhh[1 * 16 + ub];
        const float br2 = cw.bih[2 * 16 + ub] + cw.bhh[2 * 16 + ub];
        const float br3 = cw.bih[3 * 16 + ub] + cw.bhh[3 * 16 + ub];
        bs[j] = (float4v){br0 * -LOG2E, br1 * -LOG2E,
                          br2 * -2.f * LOG2E, br3 * -LOG2E};
    }

    // ---- x prologue: t=0 -> xr0, t=1 -> xr1 (l0 waves, lanes L<16).
    // L>=16 lanes keep xr == {0,0} forever -> no per-step masking needed. ----
    const float* ybase = p.y + (size_t)(b0 + n) * (T_LEN * D_IN);
    int2 xr0 = {0, 0}, xr1 = {0, 0};
    if (l == 0 && L < 16) {
        const int ta = dir ? (T_LEN - 1) : 0;
        const int tb = dir ? (T_LEN - 2) : 1;
        const float4 xa = *(const float4*)(ybase + (size_t)ta * D_IN);
        const float4 xb = *(const float4*)(ybase + (size_t)tb * D_IN);
        xr0.x = packh(xa.x, xa.y); xr0.y = packh(xa.z, xa.w);
        xr1.x = packh(xb.x, xb.y); xr1.y = packh(xb.z, xb.w);
    }

    __syncthreads();                 // prepass visible

    float cA = 0.f, cB = 0.f;        // cell state: units 8e+Q, 8e+4+Q
    float hA = 0.f, hB = 0.f;
    int ownpk = 0;                   // own e-half packed h (register)

    // One step. pr/pw literals at every call site -> static parity.
    auto STEP = [&](int s, int pr, int pw, bool a0, bool a1, bool a2,
                    int2& xr) {
        const bool act = (l == 0) ? a0 : (l == 1) ? a1 : a2;  // wave-uniform
        if (act) {
            const int sib = h_sl[pr][dir][l][1 - e][Q][n];
            int pv0, pv1;
            if (l == 0) {
                pv0 = xr.x;                     // zero in Q!=0 lanes by constr.
                pv1 = xr.y;
            } else {
                pv0 = h_sl[pr][dir][l - 1][0][Q][n];   // 256B apart ->
                pv1 = h_sl[pr][dir][l - 1][1][Q][n];   // read2st64 candidate
            }
            const h8 b8 = mk8(ownpk, sib, pv0, pv1);   // uniform for both e
            float4v p0 = MFMA32(A8[0], b8, bs[0]);     // gates of unit 8e+Q
            float4v p1 = MFMA32(A8[1], b8, bs[1]);     // gates of unit 8e+4+Q
            act2(p0, p1, cA, cB, hA, hB);
            ownpk = packh(hA, hB);
            h_sl[pw][dir][l][e][Q][n] = ownpk;
            // x prefetch 2 steps ahead into the slot just consumed
            if (l == 0 && L < 16) {
                const int t2 = s + 2;
                if (t2 < T_LEN) {
                    const int tt = dir ? (T_LEN - 1 - t2) : t2;
                    const float4 xv = *(const float4*)(ybase + (size_t)tt * D_IN);
                    xr.x = packh(xv.x, xv.y);
                    xr.y = packh(xv.z, xv.w);
                }
            }
        }
        __syncthreads();
    };

    // prologue (guarded): s=0 (l0), s=1 (l0,l1)
    STEP(0, 1, 0, true, false, false, xr0);
    STEP(1, 0, 1, true, true, false, xr1);

    // main loop: s=2..255, all layers active, branch-free, 2-step unroll
#pragma unroll 1
    for (int s = 2; s < T_LEN; s += 2) {
        STEP(s,     1, 0, true, true, true, xr0);
        STEP(s + 1, 0, 1, true, true, true, xr1);
    }

    // epilogue (guarded): s=256 (l1,l2), s=257 (l2)
    STEP(256, 1, 0, false, true, true, xr0);
    STEP(257, 0, 1, false, false, true, xr1);

    // ---- fused out_proj ----
    // l2 waves stage f32 h3 (units 8e+Q, 8e+4+Q of chain n, per dir)
    if (l == 2) {
        hf[n][dir * 16 + 8 * e + Q]     = hA;
        hf[n][dir * 16 + 8 * e + 4 + Q] = hB;
    }
    __syncthreads();
    if (tid < 64) {
        const int cn = tid >> 2, o = tid & 3;
        float acc = p.bout[o];
        const float* w = p.Wout + o * 32;
#pragma unroll
        for (int m = 0; m < 32; ++m) acc = fmaf(hf[cn][m], w[m], acc);
        p.out[(size_t)(b0 + cn) * 4 + o] = acc;
    }
}

extern "C" void kernel_launch(void* const* d_in, const int* in_sizes, int n_in,
                              void* d_out, int out_size, void* d_ws, size_t ws_size,
                              hipStream_t stream)
{
    const int B = in_sizes[0] / (T_LEN * D_IN); // 4096

    Params p;
    for (int s = 0; s < 6; ++s) {
        p.c[s].Wih = (const float*)d_in[1 + 4 * s];
        p.c[s].Whh = (const float*)d_in[2 + 4 * s];
        p.c[s].bih = (const float*)d_in[3 + 4 * s];
        p.c[s].bhh = (const float*)d_in[4 + 4 * s];
    }
    p.y = (const float*)d_in[0];
    p.Wout = (const float*)d_in[25];
    p.bout = (const float*)d_in[26];
    p.out = (float*)d_out;

    const int blocks = B / 16;               // 16 chains + both dirs per block
    lstm_wf_kernel<<<blocks, 768, 0, stream>>>(p);
}